// Round 4
// baseline (296.726 us; speedup 1.0000x reference)
//
#include <hip/hip_runtime.h>
#include <hip/hip_fp16.h>
#include <math.h>

typedef _Float16 half_t;
typedef __attribute__((ext_vector_type(2))) _Float16 f16x2;
typedef __attribute__((ext_vector_type(4))) _Float16 f16x4;
typedef __attribute__((ext_vector_type(8))) _Float16 f16x8;
typedef __attribute__((ext_vector_type(4))) float f32x4;

#define BPTT 32
#define BSZ 32
#define NTOK 2000
#define NTOKP 2048
#define NINP 1024
#define NHID 256
#define TB 1024  /* BPTT*BSZ */
#define NH2 65536
#define TCH 16   /* t-steps per chunk */
#define SCAN_LDS 33552

// LDS swizzle for 32-half (64B) rows; bijective; same function on write+read.
// Validated in R3 (SQ_LDS_BANK_CONFLICT = 0).
__device__ __forceinline__ int swz(int row, int hoff) {
  return (row * 32 + hoff) ^ ((row & 7) << 3);
}

// ---------------- conversion kernels ----------------

// merged: input -> A1hi/lo and RBF_w -> B1hi/lo (both 1024 rows x 2000->2048)
__global__ void cvt_split2_k(const float* __restrict__ inA, half_t* __restrict__ hiA,
                             half_t* __restrict__ loA, const float* __restrict__ inB,
                             half_t* __restrict__ hiB, half_t* __restrict__ loB) {
  int bid = blockIdx.x;
  const float* src;
  half_t *hi, *lo;
  int idx;
  if (bid < 8192) {
    src = inA; hi = hiA; lo = loA; idx = bid * 256 + threadIdx.x;
  } else {
    src = inB; hi = hiB; lo = loB; idx = (bid - 8192) * 256 + threadIdx.x;
  }
  int r = idx >> 11, c = idx & 2047;
  float v = (c < NTOK) ? src[(size_t)r * NTOK + c] : 0.f;
  half_t h = (half_t)v;
  hi[idx] = h;
  lo[idx] = (half_t)(v - (float)h);
}

// merged misc conversions: emb_w, wfef_b, dec_w(pad rows to 2048)
__global__ void cvt_misc_k(const float* __restrict__ emb_w,
                           const float* __restrict__ wfef_b,
                           const float* __restrict__ dec_w, half_t* __restrict__ B2,
                           half_t* __restrict__ WBh, half_t* __restrict__ B4) {
  int i = blockIdx.x * 256 + threadIdx.x;
  if (i < 262144) { B2[i] = (half_t)emb_w[i]; return; }
  i -= 262144;
  if (i < 65536) { WBh[i] = (half_t)wfef_b[i]; return; }
  i -= 65536;
  int r = i >> 8, c = i & 255;
  B4[i] = (half_t)((r < NTOK) ? dec_w[(size_t)r * 256 + c] : 0.f);
}

// WWT[h*256+r][c] = wfef_w[r*256+c][h]  (fp16 output, h-major rows)
__global__ void permute_wfef_k(const float* __restrict__ wfef, half_t* __restrict__ wwt) {
  __shared__ float tile[32][33];
  int r = blockIdx.x, cb = blockIdx.y, hb = blockIdx.z;
  int tx = threadIdx.x, ty = threadIdx.y;
#pragma unroll
  for (int ii = 0; ii < 4; ii++) {
    int cl = ty + ii * 8;
    tile[cl][tx] = wfef[((size_t)(r * 256 + cb * 32 + cl)) * 256 + hb * 32 + tx];
  }
  __syncthreads();
#pragma unroll
  for (int ii = 0; ii < 4; ii++) {
    int hl = ty + ii * 8;
    wwt[((size_t)(hb * 32 + hl) * 256 + r) * 256 + cb * 32 + tx] = (half_t)tile[tx][hl];
  }
}

// ---------------- 128x128 fp16 GEMM (256 thr), C = A @ B^T ----------------
// EP: 1 = half store (acc+bias) [obs]; 2 = f32 store [V]; 3 = f32 acc+bias,
// col guard gc<nvalid [decoder]
template <int EP>
__global__ __launch_bounds__(256) void gemm128_k(const half_t* __restrict__ A,
                                                 const half_t* __restrict__ B,
                                                 void* __restrict__ C,
                                                 const float* __restrict__ bias, int K,
                                                 int ldc, int nvalid) {
  __shared__ half_t As[128 * 32];
  __shared__ half_t Bs[128 * 32];
  const int tid = threadIdx.x;
  const int lane = tid & 63, wave = tid >> 6;
  const int wr = wave >> 1, wc = wave & 1;
  const int row0 = blockIdx.x * 128, col0 = blockIdx.y * 128;
  const int srow = tid >> 2, sseg = tid & 3;
  const size_t aoff = (size_t)(row0 + srow) * K + sseg * 8;
  const size_t boff = (size_t)(col0 + srow) * K + sseg * 8;
  const int fr = lane & 15, fq = lane >> 4;

  f32x4 acc[4][4];
#pragma unroll
  for (int m = 0; m < 4; m++)
#pragma unroll
    for (int n = 0; n < 4; n++) acc[m][n] = (f32x4)(0.0f);

  for (int k0 = 0; k0 < K; k0 += 32) {
    f16x8 a0 = *(const f16x8*)(A + aoff + k0);
    f16x8 a1 = *(const f16x8*)(A + aoff + (size_t)64 * K + k0);
    f16x8 b0 = *(const f16x8*)(B + boff + k0);
    f16x8 b1 = *(const f16x8*)(B + boff + (size_t)64 * K + k0);
    __syncthreads();
    *(f16x8*)(As + swz(srow, sseg * 8)) = a0;
    *(f16x8*)(As + swz(srow + 64, sseg * 8)) = a1;
    *(f16x8*)(Bs + swz(srow, sseg * 8)) = b0;
    *(f16x8*)(Bs + swz(srow + 64, sseg * 8)) = b1;
    __syncthreads();
    f16x8 af[4], bf[4];
#pragma unroll
    for (int m = 0; m < 4; m++)
      af[m] = *(const f16x8*)(As + swz(wr * 64 + m * 16 + fr, fq * 8));
#pragma unroll
    for (int n = 0; n < 4; n++)
      bf[n] = *(const f16x8*)(Bs + swz(wc * 64 + n * 16 + fr, fq * 8));
#pragma unroll
    for (int m = 0; m < 4; m++)
#pragma unroll
      for (int n = 0; n < 4; n++)
        acc[m][n] = __builtin_amdgcn_mfma_f32_16x16x32_f16(af[m], bf[n], acc[m][n], 0, 0, 0);
  }

#pragma unroll
  for (int m = 0; m < 4; m++) {
#pragma unroll
    for (int n = 0; n < 4; n++) {
#pragma unroll
      for (int j = 0; j < 4; j++) {
        int gr = row0 + wr * 64 + m * 16 + fq * 4 + j;
        int gc = col0 + wc * 64 + n * 16 + fr;
        float v = acc[m][n][j];
        if (EP == 1) {
          ((half_t*)C)[(size_t)gr * ldc + gc] = (half_t)(v + bias[gc]);
        } else if (EP == 2) {
          ((float*)C)[(size_t)gr * ldc + gc] = v;
        } else {
          if (gc < nvalid) ((float*)C)[(size_t)gr * ldc + gc] = v + bias[gc];
        }
      }
    }
  }
}

// ---------------- 256x256 fp16 GEMM body (1024 thr), half store ----------------
__device__ __forceinline__ void gemm256_body(const half_t* __restrict__ A,
                                             const half_t* __restrict__ B,
                                             half_t* __restrict__ C, int K, size_t ldc,
                                             int row0, int col0, char* smem) {
  half_t* As = (half_t*)smem;              // 256*32 halfs = 16 KB
  half_t* Bs = (half_t*)(smem + 16384);    // 16 KB
  const int tid = threadIdx.x;
  const int lane = tid & 63, wave = tid >> 6;  // 16 waves: 4x4 of 64x64 tiles
  const int wr = wave >> 2, wc = wave & 3;
  const int srow = tid >> 2, sseg = tid & 3;
  const size_t aoff = (size_t)(row0 + srow) * K + sseg * 8;
  const size_t boff = (size_t)(col0 + srow) * K + sseg * 8;
  const int fr = lane & 15, fq = lane >> 4;

  f32x4 acc[4][4];
#pragma unroll
  for (int m = 0; m < 4; m++)
#pragma unroll
    for (int n = 0; n < 4; n++) acc[m][n] = (f32x4)(0.0f);

  for (int k0 = 0; k0 < K; k0 += 32) {
    f16x8 a0 = *(const f16x8*)(A + aoff + k0);
    f16x8 b0 = *(const f16x8*)(B + boff + k0);
    __syncthreads();
    *(f16x8*)(As + swz(srow, sseg * 8)) = a0;
    *(f16x8*)(Bs + swz(srow, sseg * 8)) = b0;
    __syncthreads();
    f16x8 af[4], bf[4];
#pragma unroll
    for (int m = 0; m < 4; m++)
      af[m] = *(const f16x8*)(As + swz(wr * 64 + m * 16 + fr, fq * 8));
#pragma unroll
    for (int n = 0; n < 4; n++)
      bf[n] = *(const f16x8*)(Bs + swz(wc * 64 + n * 16 + fr, fq * 8));
#pragma unroll
    for (int m = 0; m < 4; m++)
#pragma unroll
      for (int n = 0; n < 4; n++)
        acc[m][n] = __builtin_amdgcn_mfma_f32_16x16x32_f16(af[m], bf[n], acc[m][n], 0, 0, 0);
  }

#pragma unroll
  for (int m = 0; m < 4; m++)
#pragma unroll
    for (int n = 0; n < 4; n++)
#pragma unroll
      for (int j = 0; j < 4; j++) {
        int gr = row0 + wr * 64 + m * 16 + fq * 4 + j;
        int gc = col0 + wc * 64 + n * 16 + fr;
        C[(size_t)gr * ldc + gc] = (half_t)acc[m][n][j];
      }
}

// ---------------- scan body: TCH steps of one sample, 1024 threads ----------------
// bn_pre[r] = sum_h b[h]*Mc[tb][h*256+r] + V[t][r]; bn = bn_pre/||bn_pre||
// wave = 16-h group; lane = (h parity, 8 r's). f16x8 loads (1KB/wave-instr).
__device__ void scan_body(const half_t* __restrict__ Mc, const float* __restrict__ V,
                          int t0, const float* __restrict__ bin,
                          float* __restrict__ bstate, half_t* __restrict__ BN,
                          float* __restrict__ bfinal, int b, char* smem) {
  float(*Vs)[256] = (float(*)[256])smem;                   // 16384 B
  float(*partial)[260] = (float(*)[260])(smem + 16384);    // 16640 B
  unsigned* bh2 = (unsigned*)(smem + 33024);               // 512 B (16-aligned)
  float* red = (float*)(smem + 33536);                     // 16 B
  const int tid = threadIdx.x;
  const int hh = tid >> 6, lane = tid & 63;
  const int hpar = lane >> 5, r8 = (lane & 31) * 8;

  *(f32x4*)&Vs[hh][lane * 4] =
      *(const f32x4*)(V + ((size_t)(t0 + hh) * 32 + b) * 256 + lane * 4);
  if (tid < 128) {
    const float* bs = bin + b * 256 + tid * 2;
    union { f16x2 h; unsigned u; } z;
    z.h[0] = (half_t)bs[0];
    z.h[1] = (half_t)bs[1];
    bh2[tid] = z.u;
  }

  // lane covers h = hh*16 + hpar + 2k (k=0..7), r in [r8, r8+8)
  const half_t* mbase = Mc + (size_t)b * NH2 + (size_t)(hh * 16 + hpar) * 256 + r8;
  f16x8 cur[8], nxt[8];
#pragma unroll
  for (int k = 0; k < 8; k++) cur[k] = *(const f16x8*)(mbase + k * 512);
  __syncthreads();

  for (int tt = 0; tt < TCH; tt++) {
    const int tn = (tt < TCH - 1) ? tt + 1 : TCH - 1;
    const half_t* mb2 = mbase + (size_t)tn * 32 * NH2;
#pragma unroll
    for (int k = 0; k < 8; k++) nxt[k] = *(const f16x8*)(mb2 + k * 512);

    // wave-uniform broadcast of packed b pairs; extract this lane's parity
    uint4 q0 = *(const uint4*)&bh2[hh * 8];
    uint4 q1 = *(const uint4*)&bh2[hh * 8 + 4];
    unsigned bu[8] = {q0.x, q0.y, q0.z, q0.w, q1.x, q1.y, q1.z, q1.w};
    const int sh = hpar * 16;
    half_t hv[8];
#pragma unroll
    for (int k = 0; k < 8; k++)
      hv[k] = __builtin_bit_cast(half_t, (unsigned short)(bu[k] >> sh));

    float a[8] = {0.f, 0.f, 0.f, 0.f, 0.f, 0.f, 0.f, 0.f};
#pragma unroll
    for (int k = 0; k < 8; k++)
#pragma unroll
      for (int j = 0; j < 8; j++) a[j] += (float)cur[k][j] * (float)hv[k];
    // combine the two h-parities
#pragma unroll
    for (int j = 0; j < 8; j++) a[j] += __shfl_xor(a[j], 32);
    // all 64 lanes store one f32x4 (16B stride pattern: measured conflict-free)
    f32x4 st = hpar ? (f32x4){a[4], a[5], a[6], a[7]} : (f32x4){a[0], a[1], a[2], a[3]};
    *(f32x4*)&partial[hh][r8 + hpar * 4] = st;
    __syncthreads();  // B1

    float s = 0.f;
    if (tid < 256) {
#pragma unroll
      for (int g = 0; g < 16; g++) s += partial[g][tid];
      s += Vs[tt][tid];
      float sq = s * s;
#pragma unroll
      for (int o = 32; o > 0; o >>= 1) sq += __shfl_xor(sq, o);
      if ((tid & 63) == 0) red[tid >> 6] = sq;
    }
    __syncthreads();  // B2
    if (tid < 256) {
      float sumsq = red[0] + red[1] + red[2] + red[3];
      float bnv = s / sqrtf(sumsq);
      float bnv_hi = __shfl_down(bnv, 1);
      if (!(tid & 1)) {
        union { f16x2 h; unsigned u; } z;
        z.h[0] = (half_t)bnv;
        z.h[1] = (half_t)bnv_hi;
        bh2[tid >> 1] = z.u;
        *(unsigned*)(BN + ((size_t)(t0 + tt) * 32 + b) * 256 + tid) = z.u;
      }
      if (tt == TCH - 1) bstate[b * 256 + tid] = bnv;
      if (t0 + tt == BPTT - 1) bfinal[b * 256 + tid] = bnv;
    }
    __syncthreads();  // B3
#pragma unroll
    for (int k = 0; k < 8; k++) cur[k] = nxt[k];
  }
}

// ---------------- top-level kernels ----------------

__global__ __launch_bounds__(1024, 4) void gemm256_k(const half_t* __restrict__ A,
                                                     const half_t* __restrict__ B,
                                                     half_t* __restrict__ C) {
  extern __shared__ char smem[];
  int id = blockIdx.x;  // 512 blocks, XCD-swizzled column slabs
  int c = id & 7, k = id >> 3;
  int bx = k & 1, by = c + 8 * (k >> 1);
  gemm256_body(A, B, C, 256, NH2, bx * 256, by * 256, smem);
}

// fused: blocks 0..31 scan chunk0; blocks 32..543 M-GEMM chunk1 (disjoint data)
__global__ __launch_bounds__(1024, 4) void fused_scan_gemm_k(
    const half_t* __restrict__ Mc, const float* __restrict__ V,
    const float* __restrict__ bin, float* __restrict__ bstate,
    half_t* __restrict__ BN, float* __restrict__ bfinal,
    const half_t* __restrict__ Ag, const half_t* __restrict__ Bg,
    half_t* __restrict__ Cg) {
  extern __shared__ char smem[];
  if (blockIdx.x < 32) {
    scan_body(Mc, V, 0, bin, bstate, BN, bfinal, blockIdx.x, smem);
  } else {
    int id = blockIdx.x - 32;
    int c = id & 7, k = id >> 3;
    int bx = k & 1, by = c + 8 * (k >> 1);
    gemm256_body(Ag, Bg, Cg, 256, NH2, bx * 256, by * 256, smem);
  }
}

__global__ __launch_bounds__(1024, 4) void scan_only_k(
    const half_t* __restrict__ Mc, const float* __restrict__ V, int t0,
    const float* __restrict__ bin, float* __restrict__ bstate,
    half_t* __restrict__ BN, float* __restrict__ bfinal) {
  extern __shared__ char smem[];
  scan_body(Mc, V, t0, bin, bstate, BN, bfinal, blockIdx.x, smem);
}

// ---------------- split-precision RBF GEMM (3-term hi/lo), split-K=4 ----------------
__global__ __launch_bounds__(256) void gemm1_splitk_k(
    const half_t* __restrict__ Ahi, const half_t* __restrict__ Alo,
    const half_t* __restrict__ Bhi, const half_t* __restrict__ Blo,
    float* __restrict__ P) {
  __shared__ half_t Ash[128 * 32];
  __shared__ half_t Asl[128 * 32];
  __shared__ half_t Bsh[64 * 32];
  __shared__ half_t Bsl[64 * 32];
  const int id = blockIdx.x;
  const int kp = id & 3, r2 = id >> 2;
  const int bx = r2 & 7, by = r2 >> 3;
  const int row0 = bx * 128, col0 = by * 64, koff = kp * 512;
  const int tid = threadIdx.x;
  const int lane = tid & 63, wave = tid >> 6;
  const int wr = wave >> 1, wc = wave & 1;
  const int srow = tid >> 2, sseg = tid & 3;
  const size_t aoff = (size_t)(row0 + srow) * NTOKP + koff + sseg * 8;
  const size_t boff = (size_t)(col0 + srow) * NTOKP + koff + sseg * 8;
  const int fr = lane & 15, fq = lane >> 4;

  f32x4 acc[4][2];
#pragma unroll
  for (int m = 0; m < 4; m++)
#pragma unroll
    for (int n = 0; n < 2; n++) acc[m][n] = (f32x4)(0.0f);

  for (int k0 = 0; k0 < 512; k0 += 32) {
    f16x8 ah0 = *(const f16x8*)(Ahi + aoff + k0);
    f16x8 ah1 = *(const f16x8*)(Ahi + aoff + (size_t)64 * NTOKP + k0);
    f16x8 al0 = *(const f16x8*)(Alo + aoff + k0);
    f16x8 al1 = *(const f16x8*)(Alo + aoff + (size_t)64 * NTOKP + k0);
    f16x8 bh0 = *(const f16x8*)(Bhi + boff + k0);
    f16x8 bl0 = *(const f16x8*)(Blo + boff + k0);
    __syncthreads();
    *(f16x8*)(Ash + swz(srow, sseg * 8)) = ah0;
    *(f16x8*)(Ash + swz(srow + 64, sseg * 8)) = ah1;
    *(f16x8*)(Asl + swz(srow, sseg * 8)) = al0;
    *(f16x8*)(Asl + swz(srow + 64, sseg * 8)) = al1;
    *(f16x8*)(Bsh + swz(srow, sseg * 8)) = bh0;
    *(f16x8*)(Bsl + swz(srow, sseg * 8)) = bl0;
    __syncthreads();
    f16x8 afh[4], afl[4], bfh[2], bfl[2];
#pragma unroll
    for (int m = 0; m < 4; m++) {
      afh[m] = *(const f16x8*)(Ash + swz(wr * 64 + m * 16 + fr, fq * 8));
      afl[m] = *(const f16x8*)(Asl + swz(wr * 64 + m * 16 + fr, fq * 8));
    }
#pragma unroll
    for (int n = 0; n < 2; n++) {
      bfh[n] = *(const f16x8*)(Bsh + swz(wc * 32 + n * 16 + fr, fq * 8));
      bfl[n] = *(const f16x8*)(Bsl + swz(wc * 32 + n * 16 + fr, fq * 8));
    }
#pragma unroll
    for (int m = 0; m < 4; m++)
#pragma unroll
      for (int n = 0; n < 2; n++) {
        acc[m][n] = __builtin_amdgcn_mfma_f32_16x16x32_f16(afh[m], bfh[n], acc[m][n], 0, 0, 0);
        acc[m][n] = __builtin_amdgcn_mfma_f32_16x16x32_f16(afl[m], bfh[n], acc[m][n], 0, 0, 0);
        acc[m][n] = __builtin_amdgcn_mfma_f32_16x16x32_f16(afh[m], bfl[n], acc[m][n], 0, 0, 0);
      }
  }

  float* Pk = P + (size_t)kp * (NINP * (size_t)TB);
#pragma unroll
  for (int m = 0; m < 4; m++)
#pragma unroll
    for (int n = 0; n < 2; n++)
#pragma unroll
      for (int j = 0; j < 4; j++) {
        int gr = row0 + wr * 64 + m * 16 + fq * 4 + j;
        int gc = col0 + wc * 32 + n * 16 + fr;
        Pk[(size_t)gr * NINP + gc] = acc[m][n][j];
      }
}

// combine split-K partials: encA = f16(cos(sum_kp P + bias) * scale)
__global__ void rbf_combine_k(const float* __restrict__ P, const float* __restrict__ bias,
                              half_t* __restrict__ C) {
  int idx = blockIdx.x * 256 + threadIdx.x;
  int e0 = idx * 4;
  int col = e0 & (NINP - 1);
  f32x4 s = *(const f32x4*)(P + e0);
  s += *(const f32x4*)(P + (size_t)1 * TB * NINP + e0);
  s += *(const f32x4*)(P + (size_t)2 * TB * NINP + e0);
  s += *(const f32x4*)(P + (size_t)3 * TB * NINP + e0);
  const float RBF_SCALE = 0.04419417382415922f;  // sqrt(2)/sqrt(1024)
  f16x4 o;
#pragma unroll
  for (int j = 0; j < 4; j++) o[j] = (half_t)(cosf(s[j] + bias[col + j]) * RBF_SCALE);
  *(f16x4*)(C + e0) = o;
}

// ---------------- launch ----------------

extern "C" void kernel_launch(void* const* d_in, const int* in_sizes, int n_in,
                              void* d_out, int out_size, void* d_ws, size_t ws_size,
                              hipStream_t stream) {
  const float* input = (const float*)d_in[0];
  const float* b0 = (const float*)d_in[1];
  const float* RBF_w = (const float*)d_in[2];
  const float* RBF_b = (const float*)d_in[3];
  const float* emb_w = (const float*)d_in[4];
  const float* emb_b = (const float*)d_in[5];
  const float* wfef_w = (const float*)d_in[6];
  const float* wfef_b = (const float*)d_in[7];
  const float* dec_w = (const float*)d_in[8];
  const float* dec_b = (const float*)d_in[9];

  char* ws = (char*)d_ws;
  size_t off = 0;
  auto alloc = [&](size_t bytes) {
    void* p = ws + off;
    off += (bytes + 255) & ~(size_t)255;
    return p;
  };
  half_t* A1hi = (half_t*)alloc((size_t)TB * NTOKP * 2);
  half_t* A1lo = (half_t*)alloc((size_t)TB * NTOKP * 2);
  half_t* B1hi = (half_t*)alloc((size_t)NINP * NTOKP * 2);
  half_t* B1lo = (half_t*)alloc((size_t)NINP * NTOKP * 2);
  half_t* encA = (half_t*)alloc((size_t)TB * NINP * 2);
  half_t* B2 = (half_t*)alloc((size_t)NHID * NINP * 2);
  half_t* obsA = (half_t*)alloc((size_t)TB * NHID * 2);
  half_t* WBh = (half_t*)alloc((size_t)NHID * NHID * 2);
  half_t* B4 = (half_t*)alloc((size_t)2048 * NHID * 2);
  float* Vbuf = (float*)alloc((size_t)TB * NHID * 4);
  half_t* BN = (half_t*)alloc((size_t)TB * NHID * 2);
  float* bstate = (float*)alloc((size_t)BSZ * NHID * 4);
  half_t* WWT = (half_t*)alloc((size_t)NH2 * NHID * 2);
  half_t* Mmat = (half_t*)alloc((size_t)TB * NH2 * 2);
  if (off > ws_size) return;  // workspace too small: fail loudly

  // split-K partials alias the (not-yet-written) Mmat region: 4x 4MB f32
  float* Pk = (float*)Mmat;

  float* outp = (float*)d_out;
  float* bfinal = outp + (size_t)TB * NTOK;

  // conversions
  cvt_split2_k<<<16384, 256, 0, stream>>>(input, A1hi, A1lo, RBF_w, B1hi, B1lo);
  cvt_misc_k<<<3328, 256, 0, stream>>>(emb_w, wfef_b, dec_w, B2, WBh, B4);
  permute_wfef_k<<<dim3(256, 8, 8), dim3(32, 8), 0, stream>>>(wfef_w, WWT);

  // encoded = cos(input @ RBF_w.T + RBF_b) * scale  [split precision, split-K=4]
  gemm1_splitk_k<<<512, 256, 0, stream>>>(A1hi, A1lo, B1hi, B1lo, Pk);
  rbf_combine_k<<<(TB * NINP / 4) / 256, 256, 0, stream>>>(Pk, RBF_b, encA);
  // obs = encoded @ emb_w.T + emb_b
  gemm128_k<1><<<dim3(8, 2), 256, 0, stream>>>(encA, B2, obsA, emb_b, NINP, NHID, 0);
  // V = obs @ reshape(wfef_b)^T
  gemm128_k<2><<<dim3(8, 2), 256, 0, stream>>>(obsA, WBh, Vbuf, nullptr, NHID, NHID, 0);

  // chunk0 M-GEMM
  gemm256_k<<<512, 1024, 32768, stream>>>(obsA, WWT, Mmat);
  // fused: scan chunk0 (32 blocks) || M-GEMM chunk1 (512 blocks)
  fused_scan_gemm_k<<<544, 1024, SCAN_LDS, stream>>>(
      Mmat, Vbuf, b0, bstate, BN, bfinal, obsA + (size_t)512 * NHID, WWT,
      Mmat + (size_t)512 * NH2);
  // scan chunk1
  scan_only_k<<<32, 1024, SCAN_LDS, stream>>>(Mmat + (size_t)512 * NH2, Vbuf, TCH,
                                              bstate, bstate, BN, bfinal);

  // outputs = BN @ dec_w.T + dec_b
  gemm128_k<3><<<dim3(8, 16), 256, 0, stream>>>(BN, B4, outp, dec_b, NHID, NTOK, NTOK);
}

// Round 5
// 229.180 us; speedup vs baseline: 1.2947x; 1.2947x over previous
//
#include <hip/hip_runtime.h>
#include <hip/hip_fp16.h>
#include <math.h>

typedef _Float16 half_t;
typedef __attribute__((ext_vector_type(2))) _Float16 f16x2;
typedef __attribute__((ext_vector_type(4))) _Float16 f16x4;
typedef __attribute__((ext_vector_type(8))) _Float16 f16x8;
typedef __attribute__((ext_vector_type(4))) float f32x4;

#define BPTT 32
#define BSZ 32
#define NTOK 2000
#define NTOKP 2048
#define NINP 1024
#define NHID 256
#define TB 1024  /* BPTT*BSZ */
#define NH2 65536
#define TCH 8          /* t-steps per chunk -> 4 chunks of 256 rows */
#define FUSED_LDS 25600
#define FRONT_LDS 24576

// LDS swizzle for 32-half (64B) rows; bijective; same fn on write+read.
// Validated in R3 (SQ_LDS_BANK_CONFLICT = 0 on scan; gemm conflicts gone).
__device__ __forceinline__ int swz(int row, int hoff) {
  return (row * 32 + hoff) ^ ((row & 7) << 3);
}

// ---------------- merged conversions (one dispatch) ----------------
__global__ void cvtAll_k(const float* __restrict__ input, half_t* __restrict__ A1hi,
                         half_t* __restrict__ A1lo, const float* __restrict__ RBF_w,
                         half_t* __restrict__ B1hi, half_t* __restrict__ B1lo,
                         const float* __restrict__ emb_w,
                         const float* __restrict__ wfef_b,
                         const float* __restrict__ dec_w, half_t* __restrict__ B2,
                         half_t* __restrict__ WBh, half_t* __restrict__ B4) {
  int bid = blockIdx.x;
  if (bid < 16384) {
    const float* src;
    half_t *hi, *lo;
    int idx;
    if (bid < 8192) {
      src = input; hi = A1hi; lo = A1lo; idx = bid * 256 + threadIdx.x;
    } else {
      src = RBF_w; hi = B1hi; lo = B1lo; idx = (bid - 8192) * 256 + threadIdx.x;
    }
    int r = idx >> 11, c = idx & 2047;
    float v = (c < NTOK) ? src[(size_t)r * NTOK + c] : 0.f;
    half_t h = (half_t)v;
    hi[idx] = h;
    lo[idx] = (half_t)(v - (float)h);
    return;
  }
  int i = (bid - 16384) * 256 + threadIdx.x;
  if (i < 262144) { B2[i] = (half_t)emb_w[i]; return; }
  i -= 262144;
  if (i < 65536) { WBh[i] = (half_t)wfef_b[i]; return; }
  i -= 65536;
  int r = i >> 8, c = i & 255;
  B4[i] = (half_t)((r < NTOK) ? dec_w[(size_t)r * 256 + c] : 0.f);
}

// ---------------- 128x128 fp16 GEMM (256 thr), C = A @ B^T ----------------
// EP: 1 = half store (acc+bias) [obs]; 2 = f32 store [V]
template <int EP>
__global__ __launch_bounds__(256) void gemm128_k(const half_t* __restrict__ A,
                                                 const half_t* __restrict__ B,
                                                 void* __restrict__ C,
                                                 const float* __restrict__ bias, int K,
                                                 int ldc) {
  __shared__ half_t As[128 * 32];
  __shared__ half_t Bs[128 * 32];
  const int tid = threadIdx.x;
  const int lane = tid & 63, wave = tid >> 6;
  const int wr = wave >> 1, wc = wave & 1;
  const int row0 = blockIdx.x * 128, col0 = blockIdx.y * 128;
  const int srow = tid >> 2, sseg = tid & 3;
  const size_t aoff = (size_t)(row0 + srow) * K + sseg * 8;
  const size_t boff = (size_t)(col0 + srow) * K + sseg * 8;
  const int fr = lane & 15, fq = lane >> 4;

  f32x4 acc[4][4];
#pragma unroll
  for (int m = 0; m < 4; m++)
#pragma unroll
    for (int n = 0; n < 4; n++) acc[m][n] = (f32x4)(0.0f);

  for (int k0 = 0; k0 < K; k0 += 32) {
    f16x8 a0 = *(const f16x8*)(A + aoff + k0);
    f16x8 a1 = *(const f16x8*)(A + aoff + (size_t)64 * K + k0);
    f16x8 b0 = *(const f16x8*)(B + boff + k0);
    f16x8 b1 = *(const f16x8*)(B + boff + (size_t)64 * K + k0);
    __syncthreads();
    *(f16x8*)(As + swz(srow, sseg * 8)) = a0;
    *(f16x8*)(As + swz(srow + 64, sseg * 8)) = a1;
    *(f16x8*)(Bs + swz(srow, sseg * 8)) = b0;
    *(f16x8*)(Bs + swz(srow + 64, sseg * 8)) = b1;
    __syncthreads();
    f16x8 af[4], bf[4];
#pragma unroll
    for (int m = 0; m < 4; m++)
      af[m] = *(const f16x8*)(As + swz(wr * 64 + m * 16 + fr, fq * 8));
#pragma unroll
    for (int n = 0; n < 4; n++)
      bf[n] = *(const f16x8*)(Bs + swz(wc * 64 + n * 16 + fr, fq * 8));
#pragma unroll
    for (int m = 0; m < 4; m++)
#pragma unroll
      for (int n = 0; n < 4; n++)
        acc[m][n] = __builtin_amdgcn_mfma_f32_16x16x32_f16(af[m], bf[n], acc[m][n], 0, 0, 0);
  }

#pragma unroll
  for (int m = 0; m < 4; m++)
#pragma unroll
    for (int n = 0; n < 4; n++)
#pragma unroll
      for (int j = 0; j < 4; j++) {
        int gr = row0 + wr * 64 + m * 16 + fq * 4 + j;
        int gc = col0 + wc * 64 + n * 16 + fr;
        float v = acc[m][n][j];
        if (EP == 1) {
          ((half_t*)C)[(size_t)gr * ldc + gc] = (half_t)(v + bias[gc]);
        } else {
          ((float*)C)[(size_t)gr * ldc + gc] = v;
        }
      }
}

// ---------------- tall-thin GEMM body: 256 rows x 128 cols, K=256, 1024 thr ----
// Same fragment/swizzle scheme as the proven 128^2 body; per-wave 64x32 tile.
// EP: 0 = half store (M precompute, ldc=NH2); 3 = f32 + bias, col guard (decoder)
template <int EP>
__device__ __forceinline__ void gemmMC_body(const half_t* __restrict__ A,
                                            const half_t* __restrict__ B,
                                            void* __restrict__ C,
                                            const float* __restrict__ bias, int col0,
                                            int ldc, int nvalid, char* smem) {
  half_t* As = (half_t*)smem;            // 256x32 halfs = 16384 B
  half_t* Bs = (half_t*)(smem + 16384);  // 128x32 halfs = 8192 B
  const int tid = threadIdx.x;
  const int lane = tid & 63, wave = tid >> 6;  // 16 waves: 4 row x 4 col
  const int wr = wave >> 2, wc = wave & 3;     // wave tile 64 rows x 32 cols
  const int srow = tid >> 2, sseg = tid & 3;
  const int fr = lane & 15, fq = lane >> 4;
  const size_t aoff = (size_t)srow * 256 + sseg * 8;
  const size_t boff = (size_t)(col0 + (srow & 127)) * 256 + sseg * 8;

  f32x4 acc[4][2];
#pragma unroll
  for (int m = 0; m < 4; m++)
#pragma unroll
    for (int n = 0; n < 2; n++) acc[m][n] = (f32x4)(0.0f);

  for (int k0 = 0; k0 < 256; k0 += 32) {
    f16x8 a0 = *(const f16x8*)(A + aoff + k0);
    f16x8 b0;
    if (tid < 512) b0 = *(const f16x8*)(B + boff + k0);
    __syncthreads();
    *(f16x8*)(As + swz(srow, sseg * 8)) = a0;
    if (tid < 512) *(f16x8*)(Bs + swz(srow, sseg * 8)) = b0;
    __syncthreads();
    f16x8 af[4], bf[2];
#pragma unroll
    for (int m = 0; m < 4; m++)
      af[m] = *(const f16x8*)(As + swz(wr * 64 + m * 16 + fr, fq * 8));
#pragma unroll
    for (int n = 0; n < 2; n++)
      bf[n] = *(const f16x8*)(Bs + swz(wc * 32 + n * 16 + fr, fq * 8));
#pragma unroll
    for (int m = 0; m < 4; m++)
#pragma unroll
      for (int n = 0; n < 2; n++)
        acc[m][n] = __builtin_amdgcn_mfma_f32_16x16x32_f16(af[m], bf[n], acc[m][n], 0, 0, 0);
  }

#pragma unroll
  for (int m = 0; m < 4; m++)
#pragma unroll
    for (int n = 0; n < 2; n++)
#pragma unroll
      for (int j = 0; j < 4; j++) {
        int gr = wr * 64 + m * 16 + fq * 4 + j;
        int gc = col0 + wc * 32 + n * 16 + fr;
        if (EP == 0) {
          ((half_t*)C)[(size_t)gr * ldc + gc] = (half_t)acc[m][n][j];
        } else {
          if (gc < nvalid)
            ((float*)C)[(size_t)gr * ldc + gc] = acc[m][n][j] + bias[gc];
        }
      }
}

// ---------------- scan body: TCH steps of one sample, 1024 threads ----------------
// Proven in R4 (passed). f16x8 M loads, double-buffered next-step prefetch.
__device__ void scan_body(const half_t* __restrict__ Mc, const float* __restrict__ V,
                          int t0, const float* __restrict__ bin,
                          float* __restrict__ bstate, half_t* __restrict__ BN,
                          float* __restrict__ bfinal, int b, char* smem) {
  float(*Vs)[256] = (float(*)[256])smem;                  // TCH*1024 = 8192 B
  float(*partial)[260] = (float(*)[260])(smem + 8192);    // 16640 B
  unsigned* bh2 = (unsigned*)(smem + 24832);              // 512 B
  float* red = (float*)(smem + 25344);                    // 16 B
  const int tid = threadIdx.x;
  const int hh = tid >> 6, lane = tid & 63;
  const int hpar = lane >> 5, r8 = (lane & 31) * 8;

  if (tid < TCH * 64) {
    int vr = tid >> 6;
    *(f32x4*)&Vs[vr][lane * 4] =
        *(const f32x4*)(V + ((size_t)(t0 + vr) * 32 + b) * 256 + lane * 4);
  }
  if (tid < 128) {
    const float* bs = bin + b * 256 + tid * 2;
    union { f16x2 h; unsigned u; } z;
    z.h[0] = (half_t)bs[0];
    z.h[1] = (half_t)bs[1];
    bh2[tid] = z.u;
  }

  // lane covers h = hh*16 + hpar + 2k (k=0..7), r in [r8, r8+8)
  const half_t* mbase = Mc + (size_t)b * NH2 + (size_t)(hh * 16 + hpar) * 256 + r8;
  f16x8 cur[8], nxt[8];
#pragma unroll
  for (int k = 0; k < 8; k++) cur[k] = *(const f16x8*)(mbase + k * 512);
  __syncthreads();

  for (int tt = 0; tt < TCH; tt++) {
    const int tn = (tt < TCH - 1) ? tt + 1 : TCH - 1;
    const half_t* mb2 = mbase + (size_t)tn * 32 * NH2;
#pragma unroll
    for (int k = 0; k < 8; k++) nxt[k] = *(const f16x8*)(mb2 + k * 512);

    uint4 q0 = *(const uint4*)&bh2[hh * 8];
    uint4 q1 = *(const uint4*)&bh2[hh * 8 + 4];
    unsigned bu[8] = {q0.x, q0.y, q0.z, q0.w, q1.x, q1.y, q1.z, q1.w};
    const int sh = hpar * 16;
    half_t hv[8];
#pragma unroll
    for (int k = 0; k < 8; k++)
      hv[k] = __builtin_bit_cast(half_t, (unsigned short)(bu[k] >> sh));

    float a[8] = {0.f, 0.f, 0.f, 0.f, 0.f, 0.f, 0.f, 0.f};
#pragma unroll
    for (int k = 0; k < 8; k++)
#pragma unroll
      for (int j = 0; j < 8; j++) a[j] += (float)cur[k][j] * (float)hv[k];
#pragma unroll
    for (int j = 0; j < 8; j++) a[j] += __shfl_xor(a[j], 32);
    f32x4 st = hpar ? (f32x4){a[4], a[5], a[6], a[7]} : (f32x4){a[0], a[1], a[2], a[3]};
    *(f32x4*)&partial[hh][r8 + hpar * 4] = st;
    __syncthreads();  // B1

    float s = 0.f;
    if (tid < 256) {
#pragma unroll
      for (int g = 0; g < 16; g++) s += partial[g][tid];
      s += Vs[tt][tid];
      float sq = s * s;
#pragma unroll
      for (int o = 32; o > 0; o >>= 1) sq += __shfl_xor(sq, o);
      if ((tid & 63) == 0) red[tid >> 6] = sq;
    }
    __syncthreads();  // B2
    if (tid < 256) {
      float sumsq = red[0] + red[1] + red[2] + red[3];
      float bnv = s / sqrtf(sumsq);
      float bnv_hi = __shfl_down(bnv, 1);
      if (!(tid & 1)) {
        union { f16x2 h; unsigned u; } z;
        z.h[0] = (half_t)bnv;
        z.h[1] = (half_t)bnv_hi;
        bh2[tid >> 1] = z.u;
        *(unsigned*)(BN + ((size_t)(t0 + tt) * 32 + b) * 256 + tid) = z.u;
      }
      if (tt == TCH - 1) bstate[b * 256 + tid] = bnv;
      if (t0 + tt == BPTT - 1) bfinal[b * 256 + tid] = bnv;
    }
    __syncthreads();  // B3
#pragma unroll
    for (int k = 0; k < 8; k++) cur[k] = nxt[k];
  }
}

// ---------------- fused top-level: [scan | M-GEMM | decoder] by block range ----
__global__ __launch_bounds__(1024) void fused_k(
    int scanN, int gemmN, const half_t* __restrict__ Msc,
    const float* __restrict__ Vbuf, int t0, const float* __restrict__ bin,
    float* __restrict__ bstate, half_t* __restrict__ BN,
    float* __restrict__ bfinal, const half_t* __restrict__ Ag,
    const half_t* __restrict__ Bg, half_t* __restrict__ Cg, int decRow0,
    const half_t* __restrict__ BNa, const half_t* __restrict__ B4,
    float* __restrict__ outp, const float* __restrict__ dec_b) {
  extern __shared__ char smem[];
  const int id = blockIdx.x;
  if (id < scanN) {
    scan_body(Msc, Vbuf, t0, bin, bstate, BN, bfinal, id, smem);
  } else if (id < scanN + gemmN) {
    const int g = id - scanN;
    gemmMC_body<0>(Ag, Bg, (void*)Cg, nullptr, g * 128, NH2, 0, smem);
  } else {
    const int d = id - scanN - gemmN;
    const int r0 = decRow0 + (d >> 4) * 256;
    gemmMC_body<3>(BNa + (size_t)r0 * 256, B4, (void*)(outp + (size_t)r0 * NTOK),
                   dec_b, (d & 15) * 128, NTOK, NTOK, smem);
  }
}

// ---------------- front: gemm1 split-K=4 (512 blocks) + wfef permute (16384) ----
__global__ __launch_bounds__(256) void front_k(const half_t* __restrict__ Ahi,
                                               const half_t* __restrict__ Alo,
                                               const half_t* __restrict__ Bhi,
                                               const half_t* __restrict__ Blo,
                                               float* __restrict__ P,
                                               const float* __restrict__ wfef,
                                               half_t* __restrict__ wwt) {
  extern __shared__ char fsm[];
  if (blockIdx.x >= 512) {
    // wfef permute: WWT[h*256+r][c] = wfef_w[r*256+c][h]
    float(*tile)[33] = (float(*)[33])fsm;
    int id2 = blockIdx.x - 512;
    int r = id2 & 255, cb = (id2 >> 8) & 7, hb = id2 >> 11;
    int tx = threadIdx.x & 31, ty = threadIdx.x >> 5;
#pragma unroll
    for (int ii = 0; ii < 4; ii++) {
      int cl = ty + ii * 8;
      tile[cl][tx] = wfef[((size_t)(r * 256 + cb * 32 + cl)) * 256 + hb * 32 + tx];
    }
    __syncthreads();
#pragma unroll
    for (int ii = 0; ii < 4; ii++) {
      int hl = ty + ii * 8;
      wwt[((size_t)(hb * 32 + hl) * 256 + r) * 256 + cb * 32 + tx] =
          (half_t)tile[tx][hl];
    }
    return;
  }
  // split-precision RBF GEMM, 128x64 tile, split-K=4
  half_t* Ash = (half_t*)fsm;              // 8192 B
  half_t* Asl = (half_t*)(fsm + 8192);     // 8192 B
  half_t* Bsh = (half_t*)(fsm + 16384);    // 4096 B
  half_t* Bsl = (half_t*)(fsm + 20480);    // 4096 B
  const int id = blockIdx.x;
  const int kp = id & 3, r2 = id >> 2;
  const int bx = r2 & 7, by = r2 >> 3;
  const int row0 = bx * 128, col0 = by * 64, koff = kp * 512;
  const int tid = threadIdx.x;
  const int lane = tid & 63, wave = tid >> 6;
  const int wr = wave >> 1, wc = wave & 1;
  const int srow = tid >> 2, sseg = tid & 3;
  const size_t aoff = (size_t)(row0 + srow) * NTOKP + koff + sseg * 8;
  const size_t boff = (size_t)(col0 + srow) * NTOKP + koff + sseg * 8;
  const int fr = lane & 15, fq = lane >> 4;

  f32x4 acc[4][2];
#pragma unroll
  for (int m = 0; m < 4; m++)
#pragma unroll
    for (int n = 0; n < 2; n++) acc[m][n] = (f32x4)(0.0f);

  for (int k0 = 0; k0 < 512; k0 += 32) {
    f16x8 ah0 = *(const f16x8*)(Ahi + aoff + k0);
    f16x8 ah1 = *(const f16x8*)(Ahi + aoff + (size_t)64 * NTOKP + k0);
    f16x8 al0 = *(const f16x8*)(Alo + aoff + k0);
    f16x8 al1 = *(const f16x8*)(Alo + aoff + (size_t)64 * NTOKP + k0);
    f16x8 bh0 = *(const f16x8*)(Bhi + boff + k0);
    f16x8 bl0 = *(const f16x8*)(Blo + boff + k0);
    __syncthreads();
    *(f16x8*)(Ash + swz(srow, sseg * 8)) = ah0;
    *(f16x8*)(Ash + swz(srow + 64, sseg * 8)) = ah1;
    *(f16x8*)(Asl + swz(srow, sseg * 8)) = al0;
    *(f16x8*)(Asl + swz(srow + 64, sseg * 8)) = al1;
    *(f16x8*)(Bsh + swz(srow, sseg * 8)) = bh0;
    *(f16x8*)(Bsl + swz(srow, sseg * 8)) = bl0;
    __syncthreads();
    f16x8 afh[4], afl[4], bfh[2], bfl[2];
#pragma unroll
    for (int m = 0; m < 4; m++) {
      afh[m] = *(const f16x8*)(Ash + swz(wr * 64 + m * 16 + fr, fq * 8));
      afl[m] = *(const f16x8*)(Asl + swz(wr * 64 + m * 16 + fr, fq * 8));
    }
#pragma unroll
    for (int n = 0; n < 2; n++) {
      bfh[n] = *(const f16x8*)(Bsh + swz(wc * 32 + n * 16 + fr, fq * 8));
      bfl[n] = *(const f16x8*)(Bsl + swz(wc * 32 + n * 16 + fr, fq * 8));
    }
#pragma unroll
    for (int m = 0; m < 4; m++)
#pragma unroll
      for (int n = 0; n < 2; n++) {
        acc[m][n] = __builtin_amdgcn_mfma_f32_16x16x32_f16(afh[m], bfh[n], acc[m][n], 0, 0, 0);
        acc[m][n] = __builtin_amdgcn_mfma_f32_16x16x32_f16(afl[m], bfh[n], acc[m][n], 0, 0, 0);
        acc[m][n] = __builtin_amdgcn_mfma_f32_16x16x32_f16(afh[m], bfl[n], acc[m][n], 0, 0, 0);
      }
  }

  float* Pk = P + (size_t)kp * (NINP * (size_t)TB);
#pragma unroll
  for (int m = 0; m < 4; m++)
#pragma unroll
    for (int n = 0; n < 2; n++)
#pragma unroll
      for (int j = 0; j < 4; j++) {
        int gr = row0 + wr * 64 + m * 16 + fq * 4 + j;
        int gc = col0 + wc * 32 + n * 16 + fr;
        Pk[(size_t)gr * NINP + gc] = acc[m][n][j];
      }
}

// combine split-K partials: encA = f16(cos(sum_kp P + bias) * scale)
__global__ void rbf_combine_k(const float* __restrict__ P, const float* __restrict__ bias,
                              half_t* __restrict__ C) {
  int idx = blockIdx.x * 256 + threadIdx.x;
  int e0 = idx * 4;
  int col = e0 & (NINP - 1);
  f32x4 s = *(const f32x4*)(P + e0);
  s += *(const f32x4*)(P + (size_t)1 * TB * NINP + e0);
  s += *(const f32x4*)(P + (size_t)2 * TB * NINP + e0);
  s += *(const f32x4*)(P + (size_t)3 * TB * NINP + e0);
  const float RBF_SCALE = 0.04419417382415922f;  // sqrt(2)/sqrt(1024)
  f16x4 o;
#pragma unroll
  for (int j = 0; j < 4; j++) o[j] = (half_t)(cosf(s[j] + bias[col + j]) * RBF_SCALE);
  *(f16x4*)(C + e0) = o;
}

// ---------------- launch ----------------

extern "C" void kernel_launch(void* const* d_in, const int* in_sizes, int n_in,
                              void* d_out, int out_size, void* d_ws, size_t ws_size,
                              hipStream_t stream) {
  const float* input = (const float*)d_in[0];
  const float* b0 = (const float*)d_in[1];
  const float* RBF_w = (const float*)d_in[2];
  const float* RBF_b = (const float*)d_in[3];
  const float* emb_w = (const float*)d_in[4];
  const float* emb_b = (const float*)d_in[5];
  const float* wfef_w = (const float*)d_in[6];
  const float* wfef_b = (const float*)d_in[7];
  const float* dec_w = (const float*)d_in[8];
  const float* dec_b = (const float*)d_in[9];

  char* ws = (char*)d_ws;
  size_t off = 0;
  auto alloc = [&](size_t bytes) {
    void* p = ws + off;
    off += (bytes + 255) & ~(size_t)255;
    return p;
  };
  half_t* A1hi = (half_t*)alloc((size_t)TB * NTOKP * 2);
  half_t* A1lo = (half_t*)alloc((size_t)TB * NTOKP * 2);
  half_t* B1hi = (half_t*)alloc((size_t)NINP * NTOKP * 2);
  half_t* B1lo = (half_t*)alloc((size_t)NINP * NTOKP * 2);
  half_t* encA = (half_t*)alloc((size_t)TB * NINP * 2);
  half_t* B2 = (half_t*)alloc((size_t)NHID * NINP * 2);
  half_t* obsA = (half_t*)alloc((size_t)TB * NHID * 2);
  half_t* WBh = (half_t*)alloc((size_t)NHID * NHID * 2);
  half_t* B4 = (half_t*)alloc((size_t)2048 * NHID * 2);
  float* Vbuf = (float*)alloc((size_t)TB * NHID * 4);
  half_t* BN = (half_t*)alloc((size_t)TB * NHID * 2);
  float* bstate = (float*)alloc((size_t)BSZ * NHID * 4);
  half_t* WWT = (half_t*)alloc((size_t)NH2 * NHID * 2);
  half_t* Mmat = (half_t*)alloc((size_t)TB * NH2 * 2);
  if (off > ws_size) return;  // workspace too small: fail loudly

  // split-K partials alias the (not-yet-written) Mmat region: 4x 4MB f32
  float* Pk = (float*)Mmat;

  float* outp = (float*)d_out;
  float* bfinal = outp + (size_t)TB * NTOK;

  // D1: all conversions
  cvtAll_k<<<19712, 256, 0, stream>>>(input, A1hi, A1lo, RBF_w, B1hi, B1lo, emb_w,
                                      wfef_b, dec_w, B2, WBh, B4);
  // D2: RBF GEMM (split-K) + wfef permute fused
  front_k<<<512 + 16384, 256, FRONT_LDS, stream>>>(A1hi, A1lo, B1hi, B1lo, Pk,
                                                   wfef_w, WWT);
  // D3: combine + cos
  rbf_combine_k<<<(TB * NINP / 4) / 256, 256, 0, stream>>>(Pk, RBF_b, encA);
  // D4: obs = encoded @ emb_w.T + emb_b
  gemm128_k<1><<<dim3(8, 2), 256, 0, stream>>>(encA, B2, obsA, emb_b, NINP, NHID);
  // D5: V = obs @ reshape(wfef_b)^T
  gemm128_k<2><<<dim3(8, 2), 256, 0, stream>>>(obsA, WBh, Vbuf, nullptr, NHID, NHID);

  // D6: M-GEMM chunk0 (no scan yet)
  fused_k<<<512, 1024, FUSED_LDS, stream>>>(
      0, 512, nullptr, Vbuf, 0, b0, bstate, BN, bfinal, obsA, WWT, Mmat, 0, BN, B4,
      outp, dec_b);
  // D7..D9: scan chunk tc || M-GEMM chunk tc+1
  for (int tc = 0; tc < 3; tc++) {
    fused_k<<<544, 1024, FUSED_LDS, stream>>>(
        32, 512, Mmat + (size_t)tc * 256 * NH2, Vbuf, tc * TCH,
        (tc == 0) ? b0 : bstate, bstate, BN, bfinal,
        obsA + (size_t)(tc + 1) * 256 * NHID, WWT, Mmat + (size_t)(tc + 1) * 256 * NH2,
        0, BN, B4, outp, dec_b);
  }
  // D10: scan chunk3 || decoder rows 0..767 (48 blocks)
  fused_k<<<32 + 48, 1024, FUSED_LDS, stream>>>(
      32, 0, Mmat + (size_t)3 * 256 * NH2, Vbuf, 3 * TCH, bstate, bstate, BN, bfinal,
      nullptr, nullptr, nullptr, 0, BN, B4, outp, dec_b);
  // D11: decoder tail rows 768..1023 (16 blocks)
  fused_k<<<16, 1024, FUSED_LDS, stream>>>(
      0, 0, nullptr, Vbuf, 0, bstate, bstate, BN, bfinal, nullptr, nullptr, nullptr,
      768, BN, B4, outp, dec_b);
}

// Round 6
// 224.283 us; speedup vs baseline: 1.3230x; 1.0218x over previous
//
#include <hip/hip_runtime.h>
#include <hip/hip_fp16.h>
#include <math.h>

typedef _Float16 half_t;
typedef __attribute__((ext_vector_type(2))) _Float16 f16x2;
typedef __attribute__((ext_vector_type(4))) _Float16 f16x4;
typedef __attribute__((ext_vector_type(8))) _Float16 f16x8;
typedef __attribute__((ext_vector_type(4))) float f32x4;

#define BPTT 32
#define BSZ 32
#define NTOK 2000
#define NTOKP 2048
#define NINP 1024
#define NHID 256
#define TB 1024  /* BPTT*BSZ */
#define NH2 65536
#define TCH 8          /* t-steps per chunk -> 4 chunks of 256 rows */
#define FUSED_LDS 25600
#define FRONT_LDS 24576

// LDS swizzle for 32-half (64B) rows; bijective; same fn on write+read.
// Validated in R3 (SQ_LDS_BANK_CONFLICT = 0 on scan; gemm conflicts gone).
__device__ __forceinline__ int swz(int row, int hoff) {
  return (row * 32 + hoff) ^ ((row & 7) << 3);
}

// ---------------- merged conversions (one dispatch) ----------------
__global__ void cvtAll_k(const float* __restrict__ input, half_t* __restrict__ A1hi,
                         half_t* __restrict__ A1lo, const float* __restrict__ RBF_w,
                         half_t* __restrict__ B1hi, half_t* __restrict__ B1lo,
                         const float* __restrict__ emb_w,
                         const float* __restrict__ wfef_b,
                         const float* __restrict__ dec_w, half_t* __restrict__ B2,
                         half_t* __restrict__ WBh, half_t* __restrict__ B4) {
  int bid = blockIdx.x;
  if (bid < 16384) {
    const float* src;
    half_t *hi, *lo;
    int idx;
    if (bid < 8192) {
      src = input; hi = A1hi; lo = A1lo; idx = bid * 256 + threadIdx.x;
    } else {
      src = RBF_w; hi = B1hi; lo = B1lo; idx = (bid - 8192) * 256 + threadIdx.x;
    }
    int r = idx >> 11, c = idx & 2047;
    float v = (c < NTOK) ? src[(size_t)r * NTOK + c] : 0.f;
    half_t h = (half_t)v;
    hi[idx] = h;
    lo[idx] = (half_t)(v - (float)h);
    return;
  }
  int i = (bid - 16384) * 256 + threadIdx.x;
  if (i < 262144) { B2[i] = (half_t)emb_w[i]; return; }
  i -= 262144;
  if (i < 65536) { WBh[i] = (half_t)wfef_b[i]; return; }
  i -= 65536;
  int r = i >> 8, c = i & 255;
  B4[i] = (half_t)((r < NTOK) ? dec_w[(size_t)r * 256 + c] : 0.f);
}

// ---------------- 128x128 fp16 GEMM (256 thr), C = A @ B^T ----------------
// EP: 1 = half store (acc+bias) [obs]; 2 = f32 store [V]
template <int EP>
__global__ __launch_bounds__(256) void gemm128_k(const half_t* __restrict__ A,
                                                 const half_t* __restrict__ B,
                                                 void* __restrict__ C,
                                                 const float* __restrict__ bias, int K,
                                                 int ldc) {
  __shared__ half_t As[128 * 32];
  __shared__ half_t Bs[128 * 32];
  const int tid = threadIdx.x;
  const int lane = tid & 63, wave = tid >> 6;
  const int wr = wave >> 1, wc = wave & 1;
  const int row0 = blockIdx.x * 128, col0 = blockIdx.y * 128;
  const int srow = tid >> 2, sseg = tid & 3;
  const size_t aoff = (size_t)(row0 + srow) * K + sseg * 8;
  const size_t boff = (size_t)(col0 + srow) * K + sseg * 8;
  const int fr = lane & 15, fq = lane >> 4;

  f32x4 acc[4][4];
#pragma unroll
  for (int m = 0; m < 4; m++)
#pragma unroll
    for (int n = 0; n < 4; n++) acc[m][n] = (f32x4)(0.0f);

  for (int k0 = 0; k0 < K; k0 += 32) {
    f16x8 a0 = *(const f16x8*)(A + aoff + k0);
    f16x8 a1 = *(const f16x8*)(A + aoff + (size_t)64 * K + k0);
    f16x8 b0 = *(const f16x8*)(B + boff + k0);
    f16x8 b1 = *(const f16x8*)(B + boff + (size_t)64 * K + k0);
    __syncthreads();
    *(f16x8*)(As + swz(srow, sseg * 8)) = a0;
    *(f16x8*)(As + swz(srow + 64, sseg * 8)) = a1;
    *(f16x8*)(Bs + swz(srow, sseg * 8)) = b0;
    *(f16x8*)(Bs + swz(srow + 64, sseg * 8)) = b1;
    __syncthreads();
    f16x8 af[4], bf[4];
#pragma unroll
    for (int m = 0; m < 4; m++)
      af[m] = *(const f16x8*)(As + swz(wr * 64 + m * 16 + fr, fq * 8));
#pragma unroll
    for (int n = 0; n < 4; n++)
      bf[n] = *(const f16x8*)(Bs + swz(wc * 64 + n * 16 + fr, fq * 8));
#pragma unroll
    for (int m = 0; m < 4; m++)
#pragma unroll
      for (int n = 0; n < 4; n++)
        acc[m][n] = __builtin_amdgcn_mfma_f32_16x16x32_f16(af[m], bf[n], acc[m][n], 0, 0, 0);
  }

#pragma unroll
  for (int m = 0; m < 4; m++)
#pragma unroll
    for (int n = 0; n < 4; n++)
#pragma unroll
      for (int j = 0; j < 4; j++) {
        int gr = row0 + wr * 64 + m * 16 + fq * 4 + j;
        int gc = col0 + wc * 64 + n * 16 + fr;
        float v = acc[m][n][j];
        if (EP == 1) {
          ((half_t*)C)[(size_t)gr * ldc + gc] = (half_t)(v + bias[gc]);
        } else {
          ((float*)C)[(size_t)gr * ldc + gc] = v;
        }
      }
}

// ---------------- tall-thin GEMM body: 256 rows x 128 cols, K=256, 1024 thr ----
// EP: 0 = half store (M precompute, ldc=NH2); 3 = f32 + bias, col guard (decoder)
template <int EP>
__device__ __forceinline__ void gemmMC_body(const half_t* __restrict__ A,
                                            const half_t* __restrict__ B,
                                            void* __restrict__ C,
                                            const float* __restrict__ bias, int col0,
                                            int ldc, int nvalid, char* smem) {
  half_t* As = (half_t*)smem;            // 256x32 halfs = 16384 B
  half_t* Bs = (half_t*)(smem + 16384);  // 128x32 halfs = 8192 B
  const int tid = threadIdx.x;
  const int lane = tid & 63, wave = tid >> 6;  // 16 waves: 4 row x 4 col
  const int wr = wave >> 2, wc = wave & 3;     // wave tile 64 rows x 32 cols
  const int srow = tid >> 2, sseg = tid & 3;
  const int fr = lane & 15, fq = lane >> 4;
  const size_t aoff = (size_t)srow * 256 + sseg * 8;
  const size_t boff = (size_t)(col0 + (srow & 127)) * 256 + sseg * 8;

  f32x4 acc[4][2];
#pragma unroll
  for (int m = 0; m < 4; m++)
#pragma unroll
    for (int n = 0; n < 2; n++) acc[m][n] = (f32x4)(0.0f);

  for (int k0 = 0; k0 < 256; k0 += 32) {
    f16x8 a0 = *(const f16x8*)(A + aoff + k0);
    f16x8 b0;
    if (tid < 512) b0 = *(const f16x8*)(B + boff + k0);
    __syncthreads();
    *(f16x8*)(As + swz(srow, sseg * 8)) = a0;
    if (tid < 512) *(f16x8*)(Bs + swz(srow, sseg * 8)) = b0;
    __syncthreads();
    f16x8 af[4], bf[2];
#pragma unroll
    for (int m = 0; m < 4; m++)
      af[m] = *(const f16x8*)(As + swz(wr * 64 + m * 16 + fr, fq * 8));
#pragma unroll
    for (int n = 0; n < 2; n++)
      bf[n] = *(const f16x8*)(Bs + swz(wc * 32 + n * 16 + fr, fq * 8));
#pragma unroll
    for (int m = 0; m < 4; m++)
#pragma unroll
      for (int n = 0; n < 2; n++)
        acc[m][n] = __builtin_amdgcn_mfma_f32_16x16x32_f16(af[m], bf[n], acc[m][n], 0, 0, 0);
  }

#pragma unroll
  for (int m = 0; m < 4; m++)
#pragma unroll
    for (int n = 0; n < 2; n++)
#pragma unroll
      for (int j = 0; j < 4; j++) {
        int gr = wr * 64 + m * 16 + fq * 4 + j;
        int gc = col0 + wc * 32 + n * 16 + fr;
        if (EP == 0) {
          ((half_t*)C)[(size_t)gr * ldc + gc] = (half_t)acc[m][n][j];
        } else {
          if (gc < nvalid)
            ((float*)C)[(size_t)gr * ldc + gc] = acc[m][n][j] + bias[gc];
        }
      }
}

// ---------------- scan body: TCH steps of one sample, 1024 threads ----------------
__device__ void scan_body(const half_t* __restrict__ Mc, const float* __restrict__ V,
                          int t0, const float* __restrict__ bin,
                          float* __restrict__ bstate, half_t* __restrict__ BN,
                          float* __restrict__ bfinal, int b, char* smem) {
  float(*Vs)[256] = (float(*)[256])smem;                  // TCH*1024 = 8192 B
  float(*partial)[260] = (float(*)[260])(smem + 8192);    // 16640 B
  unsigned* bh2 = (unsigned*)(smem + 24832);              // 512 B
  float* red = (float*)(smem + 25344);                    // 16 B
  const int tid = threadIdx.x;
  const int hh = tid >> 6, lane = tid & 63;
  const int hpar = lane >> 5, r8 = (lane & 31) * 8;

  if (tid < TCH * 64) {
    int vr = tid >> 6;
    *(f32x4*)&Vs[vr][lane * 4] =
        *(const f32x4*)(V + ((size_t)(t0 + vr) * 32 + b) * 256 + lane * 4);
  }
  if (tid < 128) {
    const float* bs = bin + b * 256 + tid * 2;
    union { f16x2 h; unsigned u; } z;
    z.h[0] = (half_t)bs[0];
    z.h[1] = (half_t)bs[1];
    bh2[tid] = z.u;
  }

  // lane covers h = hh*16 + hpar + 2k (k=0..7), r in [r8, r8+8)
  const half_t* mbase = Mc + (size_t)b * NH2 + (size_t)(hh * 16 + hpar) * 256 + r8;
  f16x8 cur[8], nxt[8];
#pragma unroll
  for (int k = 0; k < 8; k++) cur[k] = *(const f16x8*)(mbase + k * 512);
  __syncthreads();

  for (int tt = 0; tt < TCH; tt++) {
    const int tn = (tt < TCH - 1) ? tt + 1 : TCH - 1;
    const half_t* mb2 = mbase + (size_t)tn * 32 * NH2;
#pragma unroll
    for (int k = 0; k < 8; k++) nxt[k] = *(const f16x8*)(mb2 + k * 512);

    uint4 q0 = *(const uint4*)&bh2[hh * 8];
    uint4 q1 = *(const uint4*)&bh2[hh * 8 + 4];
    unsigned bu[8] = {q0.x, q0.y, q0.z, q0.w, q1.x, q1.y, q1.z, q1.w};
    const int sh = hpar * 16;
    half_t hv[8];
#pragma unroll
    for (int k = 0; k < 8; k++)
      hv[k] = __builtin_bit_cast(half_t, (unsigned short)(bu[k] >> sh));

    float a[8] = {0.f, 0.f, 0.f, 0.f, 0.f, 0.f, 0.f, 0.f};
#pragma unroll
    for (int k = 0; k < 8; k++)
#pragma unroll
      for (int j = 0; j < 8; j++) a[j] += (float)cur[k][j] * (float)hv[k];
#pragma unroll
    for (int j = 0; j < 8; j++) a[j] += __shfl_xor(a[j], 32);
    f32x4 st = hpar ? (f32x4){a[4], a[5], a[6], a[7]} : (f32x4){a[0], a[1], a[2], a[3]};
    *(f32x4*)&partial[hh][r8 + hpar * 4] = st;
    __syncthreads();  // B1

    float s = 0.f;
    if (tid < 256) {
#pragma unroll
      for (int g = 0; g < 16; g++) s += partial[g][tid];
      s += Vs[tt][tid];
      float sq = s * s;
#pragma unroll
      for (int o = 32; o > 0; o >>= 1) sq += __shfl_xor(sq, o);
      if ((tid & 63) == 0) red[tid >> 6] = sq;
    }
    __syncthreads();  // B2
    if (tid < 256) {
      float sumsq = red[0] + red[1] + red[2] + red[3];
      float bnv = s / sqrtf(sumsq);
      float bnv_hi = __shfl_down(bnv, 1);
      if (!(tid & 1)) {
        union { f16x2 h; unsigned u; } z;
        z.h[0] = (half_t)bnv;
        z.h[1] = (half_t)bnv_hi;
        bh2[tid >> 1] = z.u;
        *(unsigned*)(BN + ((size_t)(t0 + tt) * 32 + b) * 256 + tid) = z.u;
      }
      if (tt == TCH - 1) bstate[b * 256 + tid] = bnv;
      if (t0 + tt == BPTT - 1) bfinal[b * 256 + tid] = bnv;
    }
    __syncthreads();  // B3
#pragma unroll
    for (int k = 0; k < 8; k++) cur[k] = nxt[k];
  }
}

// ---------------- fused top-level: [scan | M-GEMM | decoder] by block range ----
__global__ __launch_bounds__(1024) void fused_k(
    int scanN, int gemmN, const half_t* __restrict__ Msc,
    const float* __restrict__ Vbuf, int t0, const float* __restrict__ bin,
    float* __restrict__ bstate, half_t* __restrict__ BN,
    float* __restrict__ bfinal, const half_t* __restrict__ Ag,
    const half_t* __restrict__ Bg, half_t* __restrict__ Cg, int decRow0,
    const half_t* __restrict__ BNa, const half_t* __restrict__ B4,
    float* __restrict__ outp, const float* __restrict__ dec_b) {
  extern __shared__ char smem[];
  const int id = blockIdx.x;
  if (id < scanN) {
    scan_body(Msc, Vbuf, t0, bin, bstate, BN, bfinal, id, smem);
  } else if (id < scanN + gemmN) {
    const int g = id - scanN;
    gemmMC_body<0>(Ag, Bg, (void*)Cg, nullptr, g * 128, NH2, 0, smem);
  } else {
    const int d = id - scanN - gemmN;
    const int r0 = decRow0 + (d >> 4) * 256;
    gemmMC_body<3>(BNa + (size_t)r0 * 256, B4, (void*)(outp + (size_t)r0 * NTOK),
                   dec_b, (d & 15) * 128, NTOK, NTOK, smem);
  }
}

// ---------------- front: gemm1 split-K=4 (512 blocks) + wfef transpose (4096) ----
__global__ __launch_bounds__(256) void front_k(const half_t* __restrict__ Ahi,
                                               const half_t* __restrict__ Alo,
                                               const half_t* __restrict__ Bhi,
                                               const half_t* __restrict__ Blo,
                                               float* __restrict__ P,
                                               const float* __restrict__ wfef,
                                               half_t* __restrict__ wwt) {
  extern __shared__ char fsm[];
  if (blockIdx.x >= 512) {
    // 64x64 tiled transpose: WWT[h*256+r][c] = wfef[r*256+c][h]
    // LDS f32[64][64], h-index XOR-swizzled by (c>>3): write f32x4 rows
    // (uniform bank quads), read 8 strided f32 (2 lanes/bank), store f16x8.
    float* tile = (float*)fsm;  // 16384 B
    const int p = blockIdx.x - 512;           // 0..4095
    const int r = p & 255, cb = (p >> 8) & 3, hb = p >> 10;
    const int tid = threadIdx.x;
    const int l16 = tid & 15, cr = tid >> 4;  // cr 0..15
#pragma unroll
    for (int i = 0; i < 4; i++) {
      int c = i * 16 + cr;
      int m = ((c >> 3) & 7) << 3;
      f32x4 v = *(const f32x4*)(wfef + ((size_t)(r * 256 + cb * 64 + c)) * 256 +
                                hb * 64 + l16 * 4);
      *(f32x4*)&tile[c * 64 + ((l16 * 4) ^ m)] = v;
    }
    __syncthreads();
    const int cg = tid & 7, hr = tid >> 3;  // hr 0..31
#pragma unroll
    for (int i = 0; i < 2; i++) {
      int h = i * 32 + hr;
      int hs = h ^ (cg << 3);
      f16x8 o;
#pragma unroll
      for (int j = 0; j < 8; j++) o[j] = (half_t)tile[(cg * 8 + j) * 64 + hs];
      *(f16x8*)(wwt + ((size_t)(hb * 64 + h) * 256 + r) * 256 + cb * 64 + cg * 8) = o;
    }
    return;
  }
  // split-precision RBF GEMM, 128x64 tile, split-K=4
  half_t* Ash = (half_t*)fsm;              // 8192 B
  half_t* Asl = (half_t*)(fsm + 8192);     // 8192 B
  half_t* Bsh = (half_t*)(fsm + 16384);    // 4096 B
  half_t* Bsl = (half_t*)(fsm + 20480);    // 4096 B
  const int id = blockIdx.x;
  const int kp = id & 3, r2 = id >> 2;
  const int bx = r2 & 7, by = r2 >> 3;
  const int row0 = bx * 128, col0 = by * 64, koff = kp * 512;
  const int tid = threadIdx.x;
  const int lane = tid & 63, wave = tid >> 6;
  const int wr = wave >> 1, wc = wave & 1;
  const int srow = tid >> 2, sseg = tid & 3;
  const size_t aoff = (size_t)(row0 + srow) * NTOKP + koff + sseg * 8;
  const size_t boff = (size_t)(col0 + srow) * NTOKP + koff + sseg * 8;
  const int fr = lane & 15, fq = lane >> 4;

  f32x4 acc[4][2];
#pragma unroll
  for (int m = 0; m < 4; m++)
#pragma unroll
    for (int n = 0; n < 2; n++) acc[m][n] = (f32x4)(0.0f);

  for (int k0 = 0; k0 < 512; k0 += 32) {
    f16x8 ah0 = *(const f16x8*)(Ahi + aoff + k0);
    f16x8 ah1 = *(const f16x8*)(Ahi + aoff + (size_t)64 * NTOKP + k0);
    f16x8 al0 = *(const f16x8*)(Alo + aoff + k0);
    f16x8 al1 = *(const f16x8*)(Alo + aoff + (size_t)64 * NTOKP + k0);
    f16x8 bh0 = *(const f16x8*)(Bhi + boff + k0);
    f16x8 bl0 = *(const f16x8*)(Blo + boff + k0);
    __syncthreads();
    *(f16x8*)(Ash + swz(srow, sseg * 8)) = ah0;
    *(f16x8*)(Ash + swz(srow + 64, sseg * 8)) = ah1;
    *(f16x8*)(Asl + swz(srow, sseg * 8)) = al0;
    *(f16x8*)(Asl + swz(srow + 64, sseg * 8)) = al1;
    *(f16x8*)(Bsh + swz(srow, sseg * 8)) = bh0;
    *(f16x8*)(Bsl + swz(srow, sseg * 8)) = bl0;
    __syncthreads();
    f16x8 afh[4], afl[4], bfh[2], bfl[2];
#pragma unroll
    for (int m = 0; m < 4; m++) {
      afh[m] = *(const f16x8*)(Ash + swz(wr * 64 + m * 16 + fr, fq * 8));
      afl[m] = *(const f16x8*)(Asl + swz(wr * 64 + m * 16 + fr, fq * 8));
    }
#pragma unroll
    for (int n = 0; n < 2; n++) {
      bfh[n] = *(const f16x8*)(Bsh + swz(wc * 32 + n * 16 + fr, fq * 8));
      bfl[n] = *(const f16x8*)(Bsl + swz(wc * 32 + n * 16 + fr, fq * 8));
    }
#pragma unroll
    for (int m = 0; m < 4; m++)
#pragma unroll
      for (int n = 0; n < 2; n++) {
        acc[m][n] = __builtin_amdgcn_mfma_f32_16x16x32_f16(afh[m], bfh[n], acc[m][n], 0, 0, 0);
        acc[m][n] = __builtin_amdgcn_mfma_f32_16x16x32_f16(afl[m], bfh[n], acc[m][n], 0, 0, 0);
        acc[m][n] = __builtin_amdgcn_mfma_f32_16x16x32_f16(afh[m], bfl[n], acc[m][n], 0, 0, 0);
      }
  }

  float* Pk = P + (size_t)kp * (NINP * (size_t)TB);
#pragma unroll
  for (int m = 0; m < 4; m++)
#pragma unroll
    for (int n = 0; n < 2; n++)
#pragma unroll
      for (int j = 0; j < 4; j++) {
        int gr = row0 + wr * 64 + m * 16 + fq * 4 + j;
        int gc = col0 + wc * 32 + n * 16 + fr;
        Pk[(size_t)gr * NINP + gc] = acc[m][n][j];
      }
}

// combine split-K partials: encA = f16(cos(sum_kp P + bias) * scale)
__global__ void rbf_combine_k(const float* __restrict__ P, const float* __restrict__ bias,
                              half_t* __restrict__ C) {
  int idx = blockIdx.x * 256 + threadIdx.x;
  int e0 = idx * 4;
  int col = e0 & (NINP - 1);
  f32x4 s = *(const f32x4*)(P + e0);
  s += *(const f32x4*)(P + (size_t)1 * TB * NINP + e0);
  s += *(const f32x4*)(P + (size_t)2 * TB * NINP + e0);
  s += *(const f32x4*)(P + (size_t)3 * TB * NINP + e0);
  const float RBF_SCALE = 0.04419417382415922f;  // sqrt(2)/sqrt(1024)
  f16x4 o;
#pragma unroll
  for (int j = 0; j < 4; j++) o[j] = (half_t)(cosf(s[j] + bias[col + j]) * RBF_SCALE);
  *(f16x4*)(C + e0) = o;
}

// ---------------- launch ----------------

extern "C" void kernel_launch(void* const* d_in, const int* in_sizes, int n_in,
                              void* d_out, int out_size, void* d_ws, size_t ws_size,
                              hipStream_t stream) {
  const float* input = (const float*)d_in[0];
  const float* b0 = (const float*)d_in[1];
  const float* RBF_w = (const float*)d_in[2];
  const float* RBF_b = (const float*)d_in[3];
  const float* emb_w = (const float*)d_in[4];
  const float* emb_b = (const float*)d_in[5];
  const float* wfef_w = (const float*)d_in[6];
  const float* wfef_b = (const float*)d_in[7];
  const float* dec_w = (const float*)d_in[8];
  const float* dec_b = (const float*)d_in[9];

  char* ws = (char*)d_ws;
  size_t off = 0;
  auto alloc = [&](size_t bytes) {
    void* p = ws + off;
    off += (bytes + 255) & ~(size_t)255;
    return p;
  };
  half_t* A1hi = (half_t*)alloc((size_t)TB * NTOKP * 2);
  half_t* A1lo = (half_t*)alloc((size_t)TB * NTOKP * 2);
  half_t* B1hi = (half_t*)alloc((size_t)NINP * NTOKP * 2);
  half_t* B1lo = (half_t*)alloc((size_t)NINP * NTOKP * 2);
  half_t* encA = (half_t*)alloc((size_t)TB * NINP * 2);
  half_t* B2 = (half_t*)alloc((size_t)NHID * NINP * 2);
  half_t* obsA = (half_t*)alloc((size_t)TB * NHID * 2);
  half_t* WBh = (half_t*)alloc((size_t)NHID * NHID * 2);
  half_t* B4 = (half_t*)alloc((size_t)2048 * NHID * 2);
  float* Vbuf = (float*)alloc((size_t)TB * NHID * 4);
  half_t* BN = (half_t*)alloc((size_t)TB * NHID * 2);
  float* bstate = (float*)alloc((size_t)BSZ * NHID * 4);
  half_t* WWT = (half_t*)alloc((size_t)NH2 * NHID * 2);
  half_t* Mmat = (half_t*)alloc((size_t)TB * NH2 * 2);
  if (off > ws_size) return;  // workspace too small: fail loudly

  // split-K partials alias the (not-yet-written) Mmat region: 4x 4MB f32
  float* Pk = (float*)Mmat;

  float* outp = (float*)d_out;
  float* bfinal = outp + (size_t)TB * NTOK;

  // D1: all conversions
  cvtAll_k<<<19712, 256, 0, stream>>>(input, A1hi, A1lo, RBF_w, B1hi, B1lo, emb_w,
                                      wfef_b, dec_w, B2, WBh, B4);
  // D2: RBF GEMM (split-K) + wfef tiled transpose fused
  front_k<<<512 + 4096, 256, FRONT_LDS, stream>>>(A1hi, A1lo, B1hi, B1lo, Pk,
                                                  wfef_w, WWT);
  // D3: combine + cos
  rbf_combine_k<<<(TB * NINP / 4) / 256, 256, 0, stream>>>(Pk, RBF_b, encA);
  // D4: obs = encoded @ emb_w.T + emb_b
  gemm128_k<1><<<dim3(8, 2), 256, 0, stream>>>(encA, B2, obsA, emb_b, NINP, NHID);
  // D5: V = obs @ reshape(wfef_b)^T
  gemm128_k<2><<<dim3(8, 2), 256, 0, stream>>>(obsA, WBh, Vbuf, nullptr, NHID, NHID);

  // D6: M-GEMM chunk0
  fused_k<<<512, 1024, FUSED_LDS, stream>>>(
      0, 512, nullptr, Vbuf, 0, b0, bstate, BN, bfinal, obsA, WWT, Mmat, 0, BN, B4,
      outp, dec_b);
  // D7: scan0 || gemm1
  fused_k<<<544, 1024, FUSED_LDS, stream>>>(
      32, 512, Mmat, Vbuf, 0, b0, bstate, BN, bfinal, obsA + (size_t)256 * NHID, WWT,
      Mmat + (size_t)256 * NH2, 0, BN, B4, outp, dec_b);
  // D8: scan1 || gemm2 || dec chunk0 (16 blocks)
  fused_k<<<560, 1024, FUSED_LDS, stream>>>(
      32, 512, Mmat + (size_t)256 * NH2, Vbuf, TCH, bstate, bstate, BN, bfinal,
      obsA + (size_t)512 * NHID, WWT, Mmat + (size_t)512 * NH2, 0, BN, B4, outp,
      dec_b);
  // D9: scan2 || gemm3 || dec chunk1
  fused_k<<<560, 1024, FUSED_LDS, stream>>>(
      32, 512, Mmat + (size_t)512 * NH2, Vbuf, 2 * TCH, bstate, bstate, BN, bfinal,
      obsA + (size_t)768 * NHID, WWT, Mmat + (size_t)768 * NH2, 256, BN, B4, outp,
      dec_b);
  // D10: scan3 || dec chunk2
  fused_k<<<48, 1024, FUSED_LDS, stream>>>(
      32, 0, Mmat + (size_t)768 * NH2, Vbuf, 3 * TCH, bstate, bstate, BN, bfinal,
      nullptr, nullptr, nullptr, 512, BN, B4, outp, dec_b);
  // D11: dec chunk3 (16 blocks)
  fused_k<<<16, 1024, FUSED_LDS, stream>>>(
      0, 0, nullptr, Vbuf, 0, bstate, bstate, BN, bfinal, nullptr, nullptr, nullptr,
      768, BN, B4, outp, dec_b);
}